// Round 11
// baseline (823.073 us; speedup 1.0000x reference)
//
#include <hip/hip_runtime.h>
#include <hip/hip_bf16.h>

#define IN_F   4096
#define OUT_F  11008
#define NHIGH  2752
#define NLOW   8256
#define M_TOT  4096   // B*S = 2*2048

typedef __attribute__((ext_vector_type(8))) short bf16x8;
typedef __attribute__((ext_vector_type(4))) float f32x4;
typedef __attribute__((ext_vector_type(4))) float f32x4v;

__device__ __forceinline__ short f2bf(float f) {
    union { float f; unsigned u; } v; v.f = f;
    unsigned r = (v.u + 0x7fffu + ((v.u >> 16) & 1u)) >> 16;
    return (short)(r & 0xffffu);
}

__device__ __forceinline__ void async16(const void* g, const void* l) {
    __builtin_amdgcn_global_load_lds(
        (const __attribute__((address_space(1))) unsigned int*)g,
        (__attribute__((address_space(3))) unsigned int*)l, 16, 0, 0);
}

// ---------------- kernel 0: forward permutation fwd[cinv[n]] = n ----------------
__global__ void fwd_perm_kernel(const int* __restrict__ cinv, int* __restrict__ fwd) {
    int n = blockIdx.x * blockDim.x + threadIdx.x;
    if (n < OUT_F) fwd[cinv[n]] = n;
}

// ---------------- kernel 1: x f32 -> bf16, PACKED per K-tile: xb2[kt][m][64k] ----------------
// Panel kt holds all 4096 rows' k-elements [kt*64, kt*64+64) contiguously:
// short index = kt*262144 + m*64 + (k%64). Makes each GEMM block's per-K-tile
// A-slice (128 rows x 128 B) fully contiguous (16 KB) for direct-to-reg loads.
__global__ void cvt_x_kernel(const float* __restrict__ x, short* __restrict__ xb2) {
    const int nv = (M_TOT * IN_F) / 8;
    for (int v = blockIdx.x * blockDim.x + threadIdx.x; v < nv;
         v += gridDim.x * blockDim.x) {
        const f32x4v* p = (const f32x4v*)(x + (long)v * 8);
        f32x4v a = __builtin_nontemporal_load(p);
        f32x4v b = __builtin_nontemporal_load(p + 1);
        bf16x8 o;
        o[0] = f2bf(a[0]); o[1] = f2bf(a[1]); o[2] = f2bf(a[2]); o[3] = f2bf(a[3]);
        o[4] = f2bf(b[0]); o[5] = f2bf(b[1]); o[6] = f2bf(b[2]); o[7] = f2bf(b[3]);
        const int m  = v >> 9;          // 512 8-elem vecs per row
        const int k8 = v & 511;
        const int kt = k8 >> 3;
        const int ko = (k8 & 7) * 8;
        *(bf16x8*)(xb2 + (long)kt * 262144 + m * 64 + ko) = o;
    }
}

// ---------------- kernel 2: dequant (source-major) + scatter-permute ----------------
__global__ void dequant_kernel(const int* __restrict__ hw, const float* __restrict__ hs,
                               const int* __restrict__ lw, const float* __restrict__ s1,
                               const float* __restrict__ s2, const float* __restrict__ zp,
                               const int* __restrict__ fwd,
                               short* __restrict__ wt) {
    __shared__ short tile[64 * 66];
    const int t  = threadIdx.x;
    const int c0 = blockIdx.x * 64;
    const int k0 = blockIdx.y * 64;
    const int cl = t & 63;
    const int w  = t >> 6;

    if (c0 < NHIGH) {
        const int ci = c0 + cl;
        #pragma unroll
        for (int i = 0; i < 16; ++i) {
            const int kl = w + 4 * i;
            const int k  = k0 + kl;
            int   q   = __builtin_nontemporal_load(&hw[(long)k * NHIGH + ci]);
            float val = (float)q * hs[(k >> 7) * NHIGH + ci];
            tile[cl * 66 + kl] = f2bf(val);
        }
    } else {
        const int ci = c0 - NHIGH + cl;
        const float s2v = s2[ci];
        #pragma unroll
        for (int i = 0; i < 16; ++i) {
            const int kl = w + 4 * i;
            const int k  = k0 + kl;
            int   q   = __builtin_nontemporal_load(&lw[(long)k * NLOW + ci]);
            float val = ((float)q - zp[k]) * s1[k] * s2v;
            tile[cl * 66 + kl] = f2bf(val);
        }
    }
    __syncthreads();
    const int oc = t >> 2;
    const int kq = (t & 3) * 16;
    bf16x8 o0, o1;
    #pragma unroll
    for (int j = 0; j < 8; ++j) {
        o0[j] = tile[oc * 66 + kq + j];
        o1[j] = tile[oc * 66 + kq + 8 + j];
    }
    const int ndst = fwd[c0 + oc];
    short* dst = wt + (long)ndst * IN_F + k0 + kq;
    *(bf16x8*)dst       = o0;
    *(bf16x8*)(dst + 8) = o1;
}

// ---------------- kernel 3: 128x128 GEMM, A direct-to-reg (no A LDS), B-only LDS ----------------
// Per tile: prefetch A(T+1) global->regs (ping-pong sets) || stage B(T+1) -> LDS
// || read B(T) from LDS || 32 MFMA with A(T) regs -> VMC0+BAR.
// LDS halves (B only, 32 KB dbuf) -> LDS pipe off the critical path.
#define BM 128
#define BN 128
#define BK 64
#define KT (IN_F / BK)        // 64
#define NTIL (OUT_F / BN)     // 86
#define MTIL (M_TOT / BM)     // 32
#define NWG3 (NTIL * MTIL)    // 2752 (= 8 * 344)

#define BAR()    __builtin_amdgcn_s_barrier()
#define VMC0()   asm volatile("s_waitcnt vmcnt(0)" ::: "memory")

__global__ __launch_bounds__(256, 2) void gemm_kernel(
    const short* __restrict__ A2,   // xb2 packed [kt][4096][64] bf16
    const short* __restrict__ Bt,   // [OUT_F][IN_F] bf16
    const float* __restrict__ bias,
    float* __restrict__ C) {
    // 80 KiB alloc (B dbuf uses first 32 KiB) -> exactly 2 blocks/CU.
    __shared__ __align__(16) short lds_s[40960];
    char* const lds = (char*)lds_s;

    const int t    = threadIdx.x;
    const int lane = t & 63;
    const int w    = t >> 6;      // 0..3
    const int wr   = w >> 1;      // 0..1  (M)
    const int wc   = w & 1;       // 0..1  (N)

    // XCD-bijective swizzle + supertile GSUP=8
    const int swz   = (blockIdx.x % 8) * (NWG3 / 8) + blockIdx.x / 8;
    const int sr    = swz / (8 * NTIL);
    const int in_sr = swz % (8 * NTIL);
    const int nb    = in_sr / 8;
    const int mb    = sr * 8 + (in_sr & 7);
    const int m0    = mb * BM;
    const int n0    = nb * BN;

    // B staging: wave w rows w*32+(l>>3), source chunk pre-swizzled ((l&7)^(l>>3))*16
    const int srow = w * 32 + (lane >> 3);
    const int scb  = ((lane & 7) ^ (lane >> 3)) * 16;
    const char* gB0 = (const char*)Bt + (long)(n0 + srow) * (IN_F * 2) + scb;

    // A direct loads: per lane constant byte base within a panel
    // (byte-equivalent to R10's LDS-retrieved frag: row m0+wr*64+mi*16+(l&15),
    //  k-bytes kt*128 + (l>>4)*16 + kk*64; panel stride 4096*128 B)
    const char* gA2 = (const char*)A2
        + (long)(m0 + wr * 64 + (lane & 15)) * 128 + (lane >> 4) * 16;

    // B ds_read lane bases (rows 128 B, XOR swizzle matching staged source)
    const int rl  = (lane & 15) * 128;
    const int kb0 = ((lane >> 4) * 16) ^ ((lane & 7) << 4);
    const int kb1 = kb0 ^ 64;

#define STAGE_B(buf, ktile) do {                                                 \
        const char* _gb = gB0 + (ktile) * 128;                                   \
        char* _lb = lds + (buf) * 16384 + w * 4096 + lane * 16;                  \
        _Pragma("unroll")                                                        \
        for (int _j = 0; _j < 4; ++_j)                                           \
            async16(_gb + (long)(_j * 8) * (IN_F * 2), _lb + _j * 1024);         \
    } while (0)

#define PREF_A(areg, ktn) do {                                                   \
        const char* _pa = gA2 + (long)(ktn) * 524288;                            \
        _Pragma("unroll")                                                        \
        for (int _mi = 0; _mi < 4; ++_mi)                                        \
        _Pragma("unroll")                                                        \
        for (int _kk = 0; _kk < 2; ++_kk)                                        \
            areg[_mi][_kk] = *(const bf16x8*)(_pa + _mi * 2048 + _kk * 64);      \
    } while (0)

#define RD_B(buf) do {                                                           \
        char* _pb = lds + (buf) * 16384 + wc * 8192 + rl;                        \
        _Pragma("unroll")                                                        \
        for (int _n = 0; _n < 4; ++_n) {                                         \
            bfm[_n][0] = *(const bf16x8*)(_pb + _n * 2048 + kb0);                \
            bfm[_n][1] = *(const bf16x8*)(_pb + _n * 2048 + kb1);                \
        }                                                                        \
    } while (0)

    f32x4 acc[4][4];
    #pragma unroll
    for (int i = 0; i < 4; ++i)
        #pragma unroll
        for (int j = 0; j < 4; ++j)
            acc[i][j] = (f32x4){0.f, 0.f, 0.f, 0.f};

    bf16x8 aA[4][2], aB[4][2], bfm[4][2];

#define TILE_BODY(buf, aU, aP, ktn) do {                                         \
        PREF_A(aP, ktn);                                                         \
        STAGE_B((buf) ^ 1, ktn);                                                 \
        RD_B(buf);                                                               \
        __builtin_amdgcn_s_setprio(1);                                           \
        _Pragma("unroll")                                                        \
        for (int _m = 0; _m < 4; ++_m)                                           \
        _Pragma("unroll")                                                        \
        for (int _n = 0; _n < 4; ++_n) {                                         \
            acc[_m][_n] = __builtin_amdgcn_mfma_f32_16x16x32_bf16(               \
                aU[_m][0], bfm[_n][0], acc[_m][_n], 0, 0, 0);                    \
            acc[_m][_n] = __builtin_amdgcn_mfma_f32_16x16x32_bf16(               \
                aU[_m][1], bfm[_n][1], acc[_m][_n], 0, 0, 0);                    \
        }                                                                        \
        __builtin_amdgcn_s_setprio(0);                                           \
        VMC0(); BAR();                                                           \
    } while (0)

    // prologue: A(tile0) -> aA regs, B(tile0) -> buf0
    PREF_A(aA, 0);
    STAGE_B(0, 0);
    VMC0();
    BAR();

    #pragma unroll 1
    for (int it = 0; it < KT / 2; ++it) {
        const int kt1 = 2 * it + 1;                               // < KT always
        const int kt2 = (2 * it + 2 < KT) ? 2 * it + 2 : KT - 1;  // clamp: benign refetch
        TILE_BODY(0, aA, aB, kt1);   // compute tile 2it   (buf0), prefetch tile kt1
        TILE_BODY(1, aB, aA, kt2);   // compute tile 2it+1 (buf1), prefetch tile kt2
    }

    // epilogue: nt stores
    const int er = m0 + wr * 64 + (lane >> 4) * 4;
    const int ec = n0 + wc * 64 + (lane & 15);
    #pragma unroll
    for (int ni = 0; ni < 4; ++ni) {
        const float bv = bias[ec + ni * 16];
        #pragma unroll
        for (int mi = 0; mi < 4; ++mi) {
            #pragma unroll
            for (int r = 0; r < 4; ++r) {
                __builtin_nontemporal_store(
                    acc[mi][ni][r] + bv,
                    &C[(long)(er + mi * 16 + r) * OUT_F + ec + ni * 16]);
            }
        }
    }
}

extern "C" void kernel_launch(void* const* d_in, const int* in_sizes, int n_in,
                              void* d_out, int out_size, void* d_ws, size_t ws_size,
                              hipStream_t stream) {
    const float* x    = (const float*)d_in[0];
    const int*   hw   = (const int*)d_in[1];
    const float* hs   = (const float*)d_in[2];
    const int*   lw   = (const int*)d_in[3];
    const float* s1   = (const float*)d_in[4];
    const float* s2   = (const float*)d_in[5];
    const float* zp   = (const float*)d_in[6];
    const int*   cinv = (const int*)d_in[7];
    const float* bias = (const float*)d_in[8];
    float*       out  = (float*)d_out;

    short* wt  = (short*)d_ws;                                     // 90,177,536 B
    short* xb2 = (short*)((char*)d_ws + (size_t)OUT_F * IN_F * 2); // +33,554,432 B
    int*   fwd = (int*)((char*)d_ws + (size_t)OUT_F * IN_F * 2
                                    + (size_t)M_TOT * IN_F * 2);   // +44,032 B

    fwd_perm_kernel<<<(OUT_F + 255) / 256, 256, 0, stream>>>(cinv, fwd);
    cvt_x_kernel<<<2048, 256, 0, stream>>>(x, xb2);
    dequant_kernel<<<dim3(OUT_F / 64, IN_F / 64), 256, 0, stream>>>(
        hw, hs, lw, s1, s2, zp, fwd, wt);
    gemm_kernel<<<NWG3, 256, 0, stream>>>(xb2, wt, bias, out);
}

// Round 12
// 532.093 us; speedup vs baseline: 1.5469x; 1.5469x over previous
//
#include <hip/hip_runtime.h>
#include <hip/hip_bf16.h>

#define IN_F   4096
#define OUT_F  11008
#define NHIGH  2752
#define NLOW   8256
#define M_TOT  4096   // B*S = 2*2048

typedef __attribute__((ext_vector_type(8))) short bf16x8;
typedef __attribute__((ext_vector_type(4))) float f32x4;
typedef __attribute__((ext_vector_type(4))) float f32x4v;

__device__ __forceinline__ short f2bf(float f) {
    union { float f; unsigned u; } v; v.f = f;
    unsigned r = (v.u + 0x7fffu + ((v.u >> 16) & 1u)) >> 16;
    return (short)(r & 0xffffu);
}

__device__ __forceinline__ void async16(const void* g, const void* l) {
    __builtin_amdgcn_global_load_lds(
        (const __attribute__((address_space(1))) unsigned int*)g,
        (__attribute__((address_space(3))) unsigned int*)l, 16, 0, 0);
}

// ---------------- kernel 0: forward permutation fwd[cinv[n]] = n ----------------
__global__ void fwd_perm_kernel(const int* __restrict__ cinv, int* __restrict__ fwd) {
    int n = blockIdx.x * blockDim.x + threadIdx.x;
    if (n < OUT_F) fwd[cinv[n]] = n;
}

// ---------------- kernel 1: x f32 -> bf16 (row-major xb, as R9) ----------------
__global__ void cvt_x_kernel(const float* __restrict__ x, short* __restrict__ xb) {
    const int nv = (M_TOT * IN_F) / 8;
    for (int i = blockIdx.x * blockDim.x + threadIdx.x; i < nv;
         i += gridDim.x * blockDim.x) {
        const f32x4v* p = (const f32x4v*)(x + (long)i * 8);
        f32x4v a = __builtin_nontemporal_load(p);
        f32x4v b = __builtin_nontemporal_load(p + 1);
        bf16x8 o;
        o[0] = f2bf(a[0]); o[1] = f2bf(a[1]); o[2] = f2bf(a[2]); o[3] = f2bf(a[3]);
        o[4] = f2bf(b[0]); o[5] = f2bf(b[1]); o[6] = f2bf(b[2]); o[7] = f2bf(b[3]);
        *(bf16x8*)(xb + (long)i * 8) = o;
    }
}

// ---------------- kernel 2: dequant (source-major) + scatter-permute ----------------
__global__ void dequant_kernel(const int* __restrict__ hw, const float* __restrict__ hs,
                               const int* __restrict__ lw, const float* __restrict__ s1,
                               const float* __restrict__ s2, const float* __restrict__ zp,
                               const int* __restrict__ fwd,
                               short* __restrict__ wt) {
    __shared__ short tile[64 * 66];
    const int t  = threadIdx.x;
    const int c0 = blockIdx.x * 64;
    const int k0 = blockIdx.y * 64;
    const int cl = t & 63;
    const int w  = t >> 6;

    if (c0 < NHIGH) {
        const int ci = c0 + cl;
        #pragma unroll
        for (int i = 0; i < 16; ++i) {
            const int kl = w + 4 * i;
            const int k  = k0 + kl;
            int   q   = __builtin_nontemporal_load(&hw[(long)k * NHIGH + ci]);
            float val = (float)q * hs[(k >> 7) * NHIGH + ci];
            tile[cl * 66 + kl] = f2bf(val);
        }
    } else {
        const int ci = c0 - NHIGH + cl;
        const float s2v = s2[ci];
        #pragma unroll
        for (int i = 0; i < 16; ++i) {
            const int kl = w + 4 * i;
            const int k  = k0 + kl;
            int   q   = __builtin_nontemporal_load(&lw[(long)k * NLOW + ci]);
            float val = ((float)q - zp[k]) * s1[k] * s2v;
            tile[cl * 66 + kl] = f2bf(val);
        }
    }
    __syncthreads();
    const int oc = t >> 2;
    const int kq = (t & 3) * 16;
    bf16x8 o0, o1;
    #pragma unroll
    for (int j = 0; j < 8; ++j) {
        o0[j] = tile[oc * 66 + kq + j];
        o1[j] = tile[oc * 66 + kq + 8 + j];
    }
    const int ndst = fwd[c0 + oc];
    short* dst = wt + (long)ndst * IN_F + k0 + kq;
    *(bf16x8*)dst       = o0;
    *(bf16x8*)(dst + 8) = o1;
}

// ---------------- kernel 3: 256x256 GEMM, 4 fat waves (128x128 each) ----------------
// 1 wave/SIMD, 128 MFMA per wave per sync point -> sync overhead amortized 4x vs R9.
// kk-outer MFMA order: same-acc updates 64 instrs apart (no dep stall at 1 wave/SIMD).
// R9 single-sync body: all 32 ds_reads -> stage next tile -> 128 MFMA -> VMC0+BAR.
#define BM 256
#define BN 256
#define BK 64
#define KT (IN_F / BK)        // 64
#define NTIL (OUT_F / BN)     // 43
#define MTIL (M_TOT / BM)     // 16
#define NWG2 (NTIL * MTIL)    // 688 (= 8 * 86)

#define BAR()    __builtin_amdgcn_s_barrier()
#define VMC0()   asm volatile("s_waitcnt vmcnt(0)" ::: "memory")

__global__ __launch_bounds__(256, 1) void gemm_kernel(
    const short* __restrict__ A,    // [M_TOT][IN_F] bf16
    const short* __restrict__ Bt,   // [OUT_F][IN_F] bf16
    const float* __restrict__ bias,
    float* __restrict__ C) {
    __shared__ __align__(16) short lds_s[65536];   // 128 KiB: 2 buf x (A 32K | B 32K)
    char* const lds = (char*)lds_s;

    const int t    = threadIdx.x;
    const int lane = t & 63;
    const int w    = t >> 6;      // 0..3
    const int wr   = w >> 1;      // 0..1  (M half)
    const int wc   = w & 1;       // 0..1  (N half)

    // R9 raster: XCD-bijective swizzle + supertile (4 m-tiles per super-row)
    const int swz   = (blockIdx.x % 8) * (NWG2 / 8) + blockIdx.x / 8;
    const int sr    = swz / (4 * NTIL);
    const int in_sr = swz % (4 * NTIL);
    const int nb    = in_sr / 4;
    const int mb    = sr * 4 + (in_sr & 3);
    const int m0    = mb * BM;
    const int n0    = nb * BN;

    // staging: wave w covers rows [w*64, w*64+64) of each 256-row panel;
    // round j (0..7): row w*64 + j*8 + (l>>3); source col-byte pre-swizzled
    // ((l&7)^(l>>3))*16  (row&7 == l>>3)
    const int srow = w * 64 + (lane >> 3);
    const int scb  = ((lane & 7) ^ (lane >> 3)) * 16;
    const char* gA0 = (const char*)A  + (long)(m0 + srow) * (IN_F * 2) + scb;
    const char* gB0 = (const char*)Bt + (long)(n0 + srow) * (IN_F * 2) + scb;

    // ds_read lane bases: frag row & 7 == lane & 7 -> same XOR as R9
    const int rl  = (lane & 15) * 128;
    const int kb0 = ((lane >> 4) * 16) ^ ((lane & 7) << 4);
    const int kb1 = kb0 ^ 64;

// stage full 64 KB tile (A 32K + B 32K) into buf: 16 async16/thread
#define STAGE_T(buf, ktile) do {                                                 \
        const char* _ga = gA0 + (ktile) * 128;                                   \
        const char* _gb = gB0 + (ktile) * 128;                                   \
        char* _la = lds + (buf) * 65536 +         w * 8192 + lane * 16;          \
        char* _lb = lds + (buf) * 65536 + 32768 + w * 8192 + lane * 16;          \
        _Pragma("unroll")                                                        \
        for (int _j = 0; _j < 8; ++_j) {                                         \
            async16(_ga + (long)(_j * 8) * (IN_F * 2), _la + _j * 1024);         \
            async16(_gb + (long)(_j * 8) * (IN_F * 2), _lb + _j * 1024);         \
        }                                                                        \
    } while (0)

    f32x4 acc[8][8];
    #pragma unroll
    for (int i = 0; i < 8; ++i)
        #pragma unroll
        for (int j = 0; j < 8; ++j)
            acc[i][j] = (f32x4){0.f, 0.f, 0.f, 0.f};

    bf16x8 af[8][2], bf[8][2];

// read this wave's 128x64 A slice (16 b128) and 128x64 B slice (16 b128)
#define RD_ALL(buf) do {                                                         \
        char* _pa = lds + (buf) * 65536 +         wr * 16384 + rl;               \
        char* _pb = lds + (buf) * 65536 + 32768 + wc * 16384 + rl;               \
        _Pragma("unroll")                                                        \
        for (int _i = 0; _i < 8; ++_i) {                                         \
            af[_i][0] = *(const bf16x8*)(_pa + _i * 2048 + kb0);                 \
            af[_i][1] = *(const bf16x8*)(_pa + _i * 2048 + kb1);                 \
            bf[_i][0] = *(const bf16x8*)(_pb + _i * 2048 + kb0);                 \
            bf[_i][1] = *(const bf16x8*)(_pb + _i * 2048 + kb1);                 \
        }                                                                        \
    } while (0)

// 128 MFMA, kk OUTER: acc[m][n] revisited at distance 64 (no dep stall)
#define TILE_BODY(buf, ktn) do {                                                 \
        RD_ALL(buf);                                                             \
        STAGE_T((buf) ^ 1, ktn);                                                 \
        __builtin_amdgcn_s_setprio(1);                                           \
        _Pragma("unroll")                                                        \
        for (int _kk = 0; _kk < 2; ++_kk)                                        \
        _Pragma("unroll")                                                        \
        for (int _m = 0; _m < 8; ++_m)                                           \
        _Pragma("unroll")                                                        \
        for (int _n = 0; _n < 8; ++_n)                                           \
            acc[_m][_n] = __builtin_amdgcn_mfma_f32_16x16x32_bf16(               \
                af[_m][_kk], bf[_n][_kk], acc[_m][_n], 0, 0, 0);                 \
        __builtin_amdgcn_s_setprio(0);                                           \
        VMC0(); BAR();                                                           \
    } while (0)

    // prologue: stage tile 0 into buf0
    STAGE_T(0, 0);
    VMC0();
    BAR();

    #pragma unroll 1
    for (int it = 0; it < KT / 2; ++it) {
        const int kt1 = 2 * it + 1;                               // < KT always
        const int kt2 = (2 * it + 2 < KT) ? 2 * it + 2 : KT - 1;  // clamp: benign restage
        TILE_BODY(0, kt1);
        TILE_BODY(1, kt2);
    }

    // epilogue: nt stores. row = m0+wr*128+mi*16+(lane>>4)*4+r,
    //           col = n0+wc*128+ni*16+(lane&15)
    const int er = m0 + wr * 128 + (lane >> 4) * 4;
    const int ec = n0 + wc * 128 + (lane & 15);
    #pragma unroll
    for (int ni = 0; ni < 8; ++ni) {
        const float bv = bias[ec + ni * 16];
        #pragma unroll
        for (int mi = 0; mi < 8; ++mi) {
            #pragma unroll
            for (int r = 0; r < 4; ++r) {
                __builtin_nontemporal_store(
                    acc[mi][ni][r] + bv,
                    &C[(long)(er + mi * 16 + r) * OUT_F + ec + ni * 16]);
            }
        }
    }
}

extern "C" void kernel_launch(void* const* d_in, const int* in_sizes, int n_in,
                              void* d_out, int out_size, void* d_ws, size_t ws_size,
                              hipStream_t stream) {
    const float* x    = (const float*)d_in[0];
    const int*   hw   = (const int*)d_in[1];
    const float* hs   = (const float*)d_in[2];
    const int*   lw   = (const int*)d_in[3];
    const float* s1   = (const float*)d_in[4];
    const float* s2   = (const float*)d_in[5];
    const float* zp   = (const float*)d_in[6];
    const int*   cinv = (const int*)d_in[7];
    const float* bias = (const float*)d_in[8];
    float*       out  = (float*)d_out;

    short* wt  = (short*)d_ws;                                     // 90,177,536 B
    short* xb  = (short*)((char*)d_ws + (size_t)OUT_F * IN_F * 2); // +33,554,432 B
    int*   fwd = (int*)((char*)d_ws + (size_t)OUT_F * IN_F * 2
                                    + (size_t)M_TOT * IN_F * 2);   // +44,032 B

    fwd_perm_kernel<<<(OUT_F + 255) / 256, 256, 0, stream>>>(cinv, fwd);
    cvt_x_kernel<<<2048, 256, 0, stream>>>(x, xb);
    dequant_kernel<<<dim3(OUT_F / 64, IN_F / 64), 256, 0, stream>>>(
        hw, hs, lw, s1, s2, zp, fwd, wt);
    gemm_kernel<<<NWG2, 256, 0, stream>>>(xb, wt, bias, out);
}

// Round 13
// 509.677 us; speedup vs baseline: 1.6149x; 1.0440x over previous
//
#include <hip/hip_runtime.h>
#include <hip/hip_bf16.h>

#define IN_F   4096
#define OUT_F  11008
#define NHIGH  2752
#define NLOW   8256
#define M_TOT  4096
#define NHP    2816   // padded high N (22*128)
#define NLP    8320   // padded low N  (65*128)

typedef __attribute__((ext_vector_type(8))) short bf16x8;
typedef __attribute__((ext_vector_type(4))) float f32x4;
typedef __attribute__((ext_vector_type(4))) int   i32x4;

__device__ __forceinline__ short f2bf(float f) {
    union { float f; unsigned u; } v; v.f = f;
    unsigned r = (v.u + 0x7fffu + ((v.u >> 16) & 1u)) >> 16;
    return (short)(r & 0xffffu);
}

__device__ __forceinline__ void async16(const void* g, const void* l) {
    __builtin_amdgcn_global_load_lds(
        (const __attribute__((address_space(1))) unsigned int*)g,
        (__attribute__((address_space(3))) unsigned int*)l, 16, 0, 0);
}

// ---- T1: per-256-block high counts ----
__global__ void t1_count(const int* __restrict__ cinv, int* __restrict__ bcnt) {
    __shared__ int wtot[4];
    const int t = threadIdx.x, n = blockIdx.x * 256 + t, w = t >> 6;
    int f = (cinv[n] < NHIGH) ? 1 : 0;
    unsigned long long mask = __ballot(f);
    if ((t & 63) == 0) wtot[w] = __popcll(mask);
    __syncthreads();
    if (t == 0) bcnt[blockIdx.x] = wtot[0] + wtot[1] + wtot[2] + wtot[3];
}

// ---- T2: exclusive scan of 43 counts ----
__global__ void t2_scan(const int* __restrict__ bcnt, int* __restrict__ boff) {
    const int lane = threadIdx.x;
    int v = (lane < 43) ? bcnt[lane] : 0;
    int s = v;
    #pragma unroll
    for (int i = 1; i < 64; i <<= 1) { int u = __shfl_up(s, i); if (lane >= i) s += u; }
    if (lane < 43) boff[lane] = s - v;
}

// ---- T3: ranks + tables ----
__global__ void t3_tables(const int* __restrict__ cinv, const int* __restrict__ boff,
                          int* __restrict__ rbs, int* __restrict__ och,
                          int* __restrict__ ocl, float* __restrict__ scl,
                          const float* __restrict__ s2) {
    __shared__ int wtot[4];
    const int t = threadIdx.x, n = blockIdx.x * 256 + t;
    const int lane = t & 63, w = t >> 6;
    const int c = cinv[n];
    const int f = (c < NHIGH) ? 1 : 0;
    unsigned long long mask = __ballot(f);
    int wpre = __popcll(mask & ((1ull << lane) - 1ull));
    if (lane == 63) wtot[w] = wpre + f;
    __syncthreads();
    int off = 0;
    for (int i = 0; i < w; ++i) off += wtot[i];
    const int H = boff[blockIdx.x] + off + wpre;   // highs strictly before n
    const int r = f ? H : (n - H);
    rbs[c] = r;
    if (f) { och[r] = n; }
    else   { ocl[r] = n; scl[r] = s2[c - NHIGH]; }
}

// ---- PAD: zero pad rows, -1 pad table entries ----
__global__ void pad_kernel(signed char* __restrict__ wt8, short* __restrict__ wth,
                           int* __restrict__ och, int* __restrict__ ocl) {
    const int idx = blockIdx.x * 256 + threadIdx.x;
    if (idx < 16384) {
        ((int4*)(wt8 + (long)NLOW * IN_F))[idx] = make_int4(0, 0, 0, 0);
    } else if (idx < 49152) {
        ((int4*)((char*)wth + (long)NHIGH * IN_F * 2))[idx - 16384] = make_int4(0, 0, 0, 0);
    }
    if (idx < 64)  och[NHIGH + idx] = -1;
    else if (idx < 128) ocl[NLOW + idx - 64] = -1;
}

// ---- Q: x -> xb (bf16) + xq (i8 of x*s1, per-row scale beta) ----
__global__ void quant_kernel(const float* __restrict__ x, const float* __restrict__ s1,
                             short* __restrict__ xb, signed char* __restrict__ xq,
                             float* __restrict__ beta) {
    const int t = threadIdx.x, lane = t & 63, w = t >> 6;
    const int m = blockIdx.x * 4 + w;
    const float* xr = x + (long)m * IN_F;
    float v[64];
    float amax = 0.f;
    #pragma unroll
    for (int j = 0; j < 64; ++j) {
        const int k = j * 64 + lane;
        float xv = xr[k];
        xb[(long)m * IN_F + k] = f2bf(xv);
        v[j] = xv * s1[k];
        amax = fmaxf(amax, fabsf(v[j]));
    }
    #pragma unroll
    for (int i = 1; i < 64; i <<= 1) amax = fmaxf(amax, __shfl_xor(amax, i));
    const float inv = (amax > 0.f) ? 127.f / amax : 0.f;
    if (lane == 0) beta[m] = (amax > 0.f) ? amax / 127.f : 0.f;
    #pragma unroll
    for (int j = 0; j < 64; ++j) {
        const int k = j * 64 + lane;
        int qi = (int)rintf(v[j] * inv);
        qi = qi > 127 ? 127 : (qi < -127 ? -127 : qi);
        xq[(long)m * IN_F + k] = (signed char)qi;
    }
}

// ---- D: dequant; high -> bf16 wth[rank][k]; low -> exact i8 wt8[rank][k] ----
__global__ void dequant_kernel(const int* __restrict__ hw, const float* __restrict__ hs,
                               const int* __restrict__ lw, const float* __restrict__ zp,
                               const int* __restrict__ rbs,
                               short* __restrict__ wth, signed char* __restrict__ wt8) {
    __shared__ short tile[64 * 66];
    __shared__ signed char t8[64 * 68];
    const int t  = threadIdx.x;
    const int c0 = blockIdx.x * 64;
    const int k0 = blockIdx.y * 64;
    const int cl = t & 63;
    const int w  = t >> 6;

    if (c0 < NHIGH) {
        const int ci = c0 + cl;
        #pragma unroll
        for (int i = 0; i < 16; ++i) {
            const int kl = w + 4 * i;
            const int k  = k0 + kl;
            int q = __builtin_nontemporal_load(&hw[(long)k * NHIGH + ci]);
            tile[cl * 66 + kl] = f2bf((float)q * hs[(k >> 7) * NHIGH + ci]);
        }
        __syncthreads();
        const int oc = t >> 2;
        const int kq = (t & 3) * 16;
        bf16x8 o0, o1;
        #pragma unroll
        for (int j = 0; j < 8; ++j) {
            o0[j] = tile[oc * 66 + kq + j];
            o1[j] = tile[oc * 66 + kq + 8 + j];
        }
        const int r = rbs[c0 + oc];
        short* dst = wth + (long)r * IN_F + k0 + kq;
        *(bf16x8*)dst       = o0;
        *(bf16x8*)(dst + 8) = o1;
    } else {
        const int ci = c0 - NHIGH + cl;
        #pragma unroll
        for (int i = 0; i < 16; ++i) {
            const int kl = w + 4 * i;
            const int k  = k0 + kl;
            int q  = __builtin_nontemporal_load(&lw[(long)k * NLOW + ci]);
            int zi = (int)rintf(zp[k]);
            t8[cl * 68 + kl] = (signed char)(q - zi);
        }
        __syncthreads();
        const int oc = t >> 2;
        const int kq = (t & 3) * 16;
        union { signed char c[16]; int4 v; } u;
        #pragma unroll
        for (int j = 0; j < 16; ++j) u.c[j] = t8[oc * 68 + kq + j];
        const int r = rbs[c0 + oc];
        *(int4*)(wt8 + (long)r * IN_F + k0 + kq) = u.v;
    }
}

// ---- G: combined GEMM. high: bf16 128x128 BK=64 (R10 body). low: i8 128x128 BK=128. ----
#define HB   704                 // 22 n-tiles * 32 m-tiles
#define LBK  2080                // 65 * 32
#define NWG  (HB + LBK)          // 2784 = 8*348

#define BAR()   __builtin_amdgcn_s_barrier()
#define VMC0()  asm volatile("s_waitcnt vmcnt(0)" ::: "memory")

__global__ __launch_bounds__(256, 2) void gemm_kernel(
    const short* __restrict__ xb, const short* __restrict__ wth,
    const signed char* __restrict__ xq, const signed char* __restrict__ wt8,
    const int* __restrict__ och, const int* __restrict__ ocl,
    const float* __restrict__ scl, const float* __restrict__ beta,
    const float* __restrict__ bias, float* __restrict__ out) {
    __shared__ __align__(16) char lds[65536];   // 2 buf x (A 16K | B 16K)

    const int t    = threadIdx.x;
    const int lane = t & 63;
    const int w    = t >> 6;
    const int wr   = w >> 1;
    const int wc   = w & 1;

    // XCD-bijective swizzle, then Bresenham high/low interleave (704/2784 = 22/87)
    const int swz = (blockIdx.x % 8) * (NWG / 8) + blockIdx.x / 8;
    const int h0  = (swz * 22) / 87;
    const int h1  = ((swz + 1) * 22) / 87;
    const bool hi = (h1 > h0);
    int mb, nb;
    if (hi) { const int hb = h0;       const int in = hb % 176; nb = in / 8; mb = (hb / 176) * 8 + (in & 7); }
    else    { const int lb = swz - h0; const int in = lb % 520; nb = in / 8; mb = (lb / 520) * 8 + (in & 7); }
    const int m0 = mb * 128;
    const int n0 = nb * 128;

    // staging geometry (both modes: tile = 128 rows x 128 B)
    const int srow = w * 32 + (lane >> 3);
    const int scb  = ((lane & 7) ^ (lane >> 3)) * 16;
    // ds_read bases (both modes share byte layout)
    const int rl  = (lane & 15) * 128;
    const int kb0 = ((lane >> 4) * 16) ^ ((lane & 7) << 4);
    const int kb1 = kb0 ^ 64;

#define STAGE2(gA, gB, S, buf, kbyte) do {                                       \
        const char* _ga = (gA) + (kbyte);                                        \
        const char* _gb = (gB) + (kbyte);                                        \
        char* _la = lds + (buf) * 32768 +         w * 4096 + lane * 16;          \
        char* _lb = lds + (buf) * 32768 + 16384 + w * 4096 + lane * 16;          \
        _Pragma("unroll")                                                        \
        for (int _j = 0; _j < 4; ++_j) {                                         \
            async16(_ga + (long)(_j * 8) * (S), _la + _j * 1024);                \
            async16(_gb + (long)(_j * 8) * (S), _lb + _j * 1024);                \
        }                                                                        \
    } while (0)

    if (hi) {
        // ---------------- bf16 path (R10 body) ----------------
        const char* gA = (const char*)xb  + (long)(m0 + srow) * 8192 + scb;
        const char* gB = (const char*)wth + (long)(n0 + srow) * 8192 + scb;
        f32x4 acc[4][4];
        #pragma unroll
        for (int i = 0; i < 4; ++i)
            #pragma unroll
            for (int j = 0; j < 4; ++j) acc[i][j] = (f32x4){0.f, 0.f, 0.f, 0.f};
        bf16x8 af[4][2], bfm[4][2];

#define RD_BF(buf) do {                                                          \
        char* _pa = lds + (buf) * 32768 +         (wr * 64) * 128 + rl;          \
        char* _pb = lds + (buf) * 32768 + 16384 + (wc * 64) * 128 + rl;          \
        _Pragma("unroll")                                                        \
        for (int _i = 0; _i < 4; ++_i) {                                         \
            af[_i][0]  = *(const bf16x8*)(_pa + _i * 2048 + kb0);                \
            af[_i][1]  = *(const bf16x8*)(_pa + _i * 2048 + kb1);                \
            bfm[_i][0] = *(const bf16x8*)(_pb + _i * 2048 + kb0);                \
            bfm[_i][1] = *(const bf16x8*)(_pb + _i * 2048 + kb1);                \
        }                                                                        \
    } while (0)

#define TILE_BF(buf, ktn) do {                                                   \
        RD_BF(buf);                                                              \
        STAGE2(gA, gB, 8192, (buf) ^ 1, (long)(ktn) * 128);                      \
        __builtin_amdgcn_s_setprio(1);                                           \
        _Pragma("unroll")                                                        \
        for (int _m = 0; _m < 4; ++_m)                                           \
        _Pragma("unroll")                                                        \
        for (int _n = 0; _n < 4; ++_n) {                                         \
            acc[_m][_n] = __builtin_amdgcn_mfma_f32_16x16x32_bf16(               \
                af[_m][0], bfm[_n][0], acc[_m][_n], 0, 0, 0);                    \
            acc[_m][_n] = __builtin_amdgcn_mfma_f32_16x16x32_bf16(               \
                af[_m][1], bfm[_n][1], acc[_m][_n], 0, 0, 0);                    \
        }                                                                        \
        __builtin_amdgcn_s_setprio(0);                                           \
        VMC0(); BAR();                                                           \
    } while (0)

        STAGE2(gA, gB, 8192, 0, 0);
        VMC0(); BAR();
        #pragma unroll 1
        for (int it = 0; it < 32; ++it) {
            const int kt1 = 2 * it + 1;
            const int kt2 = (2 * it + 2 < 64) ? 2 * it + 2 : 63;
            TILE_BF(0, kt1);
            TILE_BF(1, kt2);
        }
        // epilogue: scatter to out via och (normal stores for cache merge)
        const int er  = m0 + wr * 64 + (lane >> 4) * 4;
        const int ecr = n0 + wc * 64 + (lane & 15);
        #pragma unroll
        for (int ni = 0; ni < 4; ++ni) {
            const int n = och[ecr + ni * 16];
            if (n >= 0) {
                const float bv = bias[n];
                #pragma unroll
                for (int mi = 0; mi < 4; ++mi)
                    #pragma unroll
                    for (int r = 0; r < 4; ++r)
                        out[(long)(er + mi * 16 + r) * OUT_F + n] = acc[mi][ni][r] + bv;
            }
        }
    } else {
        // ---------------- i8 path (BK=128, KT=32) ----------------
        const char* gA = (const char*)xq  + (long)(m0 + srow) * 4096 + scb;
        const char* gB = (const char*)wt8 + (long)(n0 + srow) * 4096 + scb;
        i32x4 acc[4][4];
        #pragma unroll
        for (int i = 0; i < 4; ++i)
            #pragma unroll
            for (int j = 0; j < 4; ++j) acc[i][j] = (i32x4){0, 0, 0, 0};
        i32x4 ai[4][2], bi[4][2];

#define RD_I8(buf) do {                                                          \
        char* _pa = lds + (buf) * 32768 +         (wr * 64) * 128 + rl;          \
        char* _pb = lds + (buf) * 32768 + 16384 + (wc * 64) * 128 + rl;          \
        _Pragma("unroll")                                                        \
        for (int _i = 0; _i < 4; ++_i) {                                         \
            ai[_i][0] = *(const i32x4*)(_pa + _i * 2048 + kb0);                  \
            ai[_i][1] = *(const i32x4*)(_pa + _i * 2048 + kb1);                  \
            bi[_i][0] = *(const i32x4*)(_pb + _i * 2048 + kb0);                  \
            bi[_i][1] = *(const i32x4*)(_pb + _i * 2048 + kb1);                  \
        }                                                                        \
    } while (0)

#define TILE_I8(buf, ktn) do {                                                   \
        RD_I8(buf);                                                              \
        STAGE2(gA, gB, 4096, (buf) ^ 1, (long)(ktn) * 128);                      \
        __builtin_amdgcn_s_setprio(1);                                           \
        _Pragma("unroll")                                                        \
        for (int _m = 0; _m < 4; ++_m)                                           \
        _Pragma("unroll")                                                        \
        for (int _n = 0; _n < 4; ++_n) {                                         \
            acc[_m][_n] = __builtin_amdgcn_mfma_i32_16x16x64_i8(                 \
                ai[_m][0], bi[_n][0], acc[_m][_n], 0, 0, 0);                     \
            acc[_m][_n] = __builtin_amdgcn_mfma_i32_16x16x64_i8(                 \
                ai[_m][1], bi[_n][1], acc[_m][_n], 0, 0, 0);                     \
        }                                                                        \
        __builtin_amdgcn_s_setprio(0);                                           \
        VMC0(); BAR();                                                           \
    } while (0)

        STAGE2(gA, gB, 4096, 0, 0);
        VMC0(); BAR();
        #pragma unroll 1
        for (int it = 0; it < 16; ++it) {
            const int kt1 = 2 * it + 1;
            const int kt2 = (2 * it + 2 < 32) ? 2 * it + 2 : 31;
            TILE_I8(0, kt1);
            TILE_I8(1, kt2);
        }
        // epilogue: val = acc * beta[row] * scl[rank] + bias[n]
        const int er  = m0 + wr * 64 + (lane >> 4) * 4;
        const int ecr = n0 + wc * 64 + (lane & 15);
        float bt[4][4];
        #pragma unroll
        for (int mi = 0; mi < 4; ++mi)
            #pragma unroll
            for (int r = 0; r < 4; ++r)
                bt[mi][r] = beta[er + mi * 16 + r];
        #pragma unroll
        for (int ni = 0; ni < 4; ++ni) {
            const int rk = ecr + ni * 16;
            const int n  = ocl[rk];
            if (n >= 0) {
                const float sc = scl[rk];
                const float bv = bias[n];
                #pragma unroll
                for (int mi = 0; mi < 4; ++mi)
                    #pragma unroll
                    for (int r = 0; r < 4; ++r)
                        out[(long)(er + mi * 16 + r) * OUT_F + n] =
                            (float)acc[mi][ni][r] * bt[mi][r] * sc + bv;
            }
        }
    }
}

extern "C" void kernel_launch(void* const* d_in, const int* in_sizes, int n_in,
                              void* d_out, int out_size, void* d_ws, size_t ws_size,
                              hipStream_t stream) {
    const float* x    = (const float*)d_in[0];
    const int*   hw   = (const int*)d_in[1];
    const float* hs   = (const float*)d_in[2];
    const int*   lw   = (const int*)d_in[3];
    const float* s1   = (const float*)d_in[4];
    const float* s2   = (const float*)d_in[5];
    const float* zp   = (const float*)d_in[6];
    const int*   cinv = (const int*)d_in[7];
    const float* bias = (const float*)d_in[8];
    float*       out  = (float*)d_out;

    char* p = (char*)d_ws;
    signed char* wt8  = (signed char*)p;            p += (size_t)NLP * IN_F;       // 34,078,720
    short*       wth  = (short*)p;                  p += (size_t)NHP * IN_F * 2;   // 23,068,672
    signed char* xq   = (signed char*)p;            p += (size_t)M_TOT * IN_F;     // 16,777,216
    short*       xb   = (short*)p;                  p += (size_t)M_TOT * IN_F * 2; // 33,554,432
    float*       beta = (float*)p;                  p += (size_t)M_TOT * 4;        // 16,384
    int*         och  = (int*)p;                    p += (size_t)NHP * 4;          // 11,264
    int*         ocl  = (int*)p;                    p += (size_t)NLP * 4;          // 33,280
    float*       scl  = (float*)p;                  p += (size_t)NLP * 4;          // 33,280
    int*         rbs  = (int*)p;                    p += (size_t)OUT_F * 4;        // 44,032
    int*         bcnt = (int*)p;                    p += 64 * 4;
    int*         boff = (int*)p;                    p += 64 * 4;

    t1_count<<<43, 256, 0, stream>>>(cinv, bcnt);
    t2_scan<<<1, 64, 0, stream>>>(bcnt, boff);
    t3_tables<<<43, 256, 0, stream>>>(cinv, boff, rbs, och, ocl, scl, s2);
    pad_kernel<<<192, 256, 0, stream>>>(wt8, wth, och, ocl);
    quant_kernel<<<1024, 256, 0, stream>>>(x, s1, xb, xq, beta);
    dequant_kernel<<<dim3(172, 64), 256, 0, stream>>>(hw, hs, lw, zp, rbs, wth, wt8);
    gemm_kernel<<<NWG, 256, 0, stream>>>(xb, wth, xq, wt8, och, ocl, scl, beta,
                                         bias, out);
}

// Round 14
// 393.638 us; speedup vs baseline: 2.0909x; 1.2948x over previous
//
#include <hip/hip_runtime.h>
#include <hip/hip_bf16.h>

#define IN_F   4096
#define OUT_F  11008
#define NHIGH  2752
#define NLOW   8256
#define M_TOT  4096   // B*S = 2*2048

typedef __attribute__((ext_vector_type(8))) short bf16x8;
typedef __attribute__((ext_vector_type(4))) float f32x4;
typedef __attribute__((ext_vector_type(4))) float f32x4v;

__device__ __forceinline__ short f2bf(float f) {
    union { float f; unsigned u; } v; v.f = f;
    unsigned r = (v.u + 0x7fffu + ((v.u >> 16) & 1u)) >> 16;
    return (short)(r & 0xffffu);
}

__device__ __forceinline__ void async16(const void* g, const void* l) {
    __builtin_amdgcn_global_load_lds(
        (const __attribute__((address_space(1))) unsigned int*)g,
        (__attribute__((address_space(3))) unsigned int*)l, 16, 0, 0);
}

// ---------------- kernel 0: forward permutation fwd[cinv[n]] = n ----------------
__global__ void fwd_perm_kernel(const int* __restrict__ cinv, int* __restrict__ fwd) {
    int n = blockIdx.x * blockDim.x + threadIdx.x;
    if (n < OUT_F) fwd[cinv[n]] = n;
}

// ---------------- kernel 1: x f32 -> bf16 (nt loads: read-once) ----------------
__global__ void cvt_x_kernel(const float* __restrict__ x, short* __restrict__ xb) {
    const int nv = (M_TOT * IN_F) / 8;
    for (int i = blockIdx.x * blockDim.x + threadIdx.x; i < nv;
         i += gridDim.x * blockDim.x) {
        const f32x4v* p = (const f32x4v*)(x + (long)i * 8);
        f32x4v a = __builtin_nontemporal_load(p);
        f32x4v b = __builtin_nontemporal_load(p + 1);
        bf16x8 o;
        o[0] = f2bf(a[0]); o[1] = f2bf(a[1]); o[2] = f2bf(a[2]); o[3] = f2bf(a[3]);
        o[4] = f2bf(b[0]); o[5] = f2bf(b[1]); o[6] = f2bf(b[2]); o[7] = f2bf(b[3]);
        *(bf16x8*)(xb + (long)i * 8) = o;
    }
}

// ---------------- kernel 2: dequant (source-major) + scatter-permute ----------------
__global__ void dequant_kernel(const int* __restrict__ hw, const float* __restrict__ hs,
                               const int* __restrict__ lw, const float* __restrict__ s1,
                               const float* __restrict__ s2, const float* __restrict__ zp,
                               const int* __restrict__ fwd,
                               short* __restrict__ wt) {
    __shared__ short tile[64 * 66];
    const int t  = threadIdx.x;
    const int c0 = blockIdx.x * 64;
    const int k0 = blockIdx.y * 64;
    const int cl = t & 63;
    const int w  = t >> 6;

    if (c0 < NHIGH) {
        const int ci = c0 + cl;
        #pragma unroll
        for (int i = 0; i < 16; ++i) {
            const int kl = w + 4 * i;
            const int k  = k0 + kl;
            int   q   = __builtin_nontemporal_load(&hw[(long)k * NHIGH + ci]);
            float val = (float)q * hs[(k >> 7) * NHIGH + ci];
            tile[cl * 66 + kl] = f2bf(val);
        }
    } else {
        const int ci = c0 - NHIGH + cl;
        const float s2v = s2[ci];
        #pragma unroll
        for (int i = 0; i < 16; ++i) {
            const int kl = w + 4 * i;
            const int k  = k0 + kl;
            int   q   = __builtin_nontemporal_load(&lw[(long)k * NLOW + ci]);
            float val = ((float)q - zp[k]) * s1[k] * s2v;
            tile[cl * 66 + kl] = f2bf(val);
        }
    }
    __syncthreads();
    const int oc = t >> 2;
    const int kq = (t & 3) * 16;
    bf16x8 o0, o1;
    #pragma unroll
    for (int j = 0; j < 8; ++j) {
        o0[j] = tile[oc * 66 + kq + j];
        o1[j] = tile[oc * 66 + kq + 8 + j];
    }
    const int ndst = fwd[c0 + oc];
    short* dst = wt + (long)ndst * IN_F + k0 + kq;
    *(bf16x8*)dst       = o0;
    *(bf16x8*)(dst + 8) = o1;
}

// ---------------- kernel 3: 256x256 GEMM, 1-barrier-per-K-tile, counted-lgkm overlap ----------------
// Per K-tile: issue ALL 24 ds_reads -> issue 8 STAGE loads (tile T+1 into buf^1,
// no WAR with current reads) -> 4 MFMA quadrants (compiler inserts counted
// lgkmcnt before first use of each frag set -> LDS reads overlap MFMA) ->
// VMC(0) + BAR (only sync point; staging had the whole tile to land).
#define BM 256
#define BN 256
#define BK 64
#define KT (IN_F / BK)        // 64
#define NTIL (OUT_F / BN)     // 43
#define MTIL (M_TOT / BM)     // 16
#define NWG2 (NTIL * MTIL)    // 688 (= 8 * 86)

#define BAR()    __builtin_amdgcn_s_barrier()
#define VMC0()   asm volatile("s_waitcnt vmcnt(0)" ::: "memory")

__global__ __launch_bounds__(512, 2) void gemm_kernel(
    const short* __restrict__ A,    // [M_TOT][IN_F] bf16
    const short* __restrict__ Bt,   // [OUT_F][IN_F] bf16
    const float* __restrict__ bias,
    float* __restrict__ C) {
    __shared__ __align__(16) short lds_s[65536];   // 128 KiB
    char* const lds = (char*)lds_s;

    const int t    = threadIdx.x;
    const int lane = t & 63;
    const int w    = t >> 6;      // 0..7
    const int wr   = w >> 2;      // 0..1  (M)
    const int wc   = w & 3;       // 0..3  (N)

    // R4 raster: XCD-bijective swizzle + supertile (4 m-tiles per super-row)
    const int swz   = (blockIdx.x % 8) * (NWG2 / 8) + blockIdx.x / 8;
    const int sr    = swz / (4 * NTIL);
    const int in_sr = swz % (4 * NTIL);
    const int nb    = in_sr / 4;
    const int mb    = sr * 4 + (in_sr & 3);
    const int m0    = mb * BM;
    const int n0    = nb * BN;

    // staging: wave w, lane l -> half-row w*8 + (l>>3); source col-byte
    // pre-swizzled ((l&7)^(l>>3))*16
    const int srow = w * 8 + (lane >> 3);
    const int scb  = ((lane & 7) ^ (lane >> 3)) * 16;
    const char* gA0 = (const char*)A  + (long)(m0 + srow) * (IN_F * 2) + scb;
    const char* gB0 = (const char*)Bt + (long)(n0 + srow) * (IN_F * 2) + scb;

    // ds_read lane bases
    const int rl  = (lane & 15) * 128;
    const int kb0 = ((lane >> 4) * 16) ^ ((lane & 7) << 4);
    const int kb1 = kb0 ^ 64;

#define STAGE(gbase, region_off, h, ktile) do {                                  \
        const char* _g = (gbase) + (long)((h) * 128) * (IN_F * 2) + (ktile) * 128; \
        char* _l = lds + (region_off) + (h) * 16384 + w * 1024;                  \
        async16(_g,                        _l);                                  \
        async16(_g + (long)64 * (IN_F * 2), _l + 8192);                          \
    } while (0)

    f32x4 acc[8][4];
    #pragma unroll
    for (int i = 0; i < 8; ++i)
        #pragma unroll
        for (int j = 0; j < 4; ++j)
            acc[i][j] = (f32x4){0.f, 0.f, 0.f, 0.f};

    bf16x8 aA[4][2], aB[4][2], b0[2][2], b1[2][2];

#define RD_A(buf, mq, areg) do {                                                 \
        char* _p = lds + (buf) * 65536 + wr * 16384 + (mq) * 8192 + rl;          \
        _Pragma("unroll")                                                        \
        for (int _j = 0; _j < 4; ++_j) {                                         \
            areg[_j][0] = *(const bf16x8*)(_p + _j * 2048 + kb0);                \
            areg[_j][1] = *(const bf16x8*)(_p + _j * 2048 + kb1);                \
        }                                                                        \
    } while (0)

#define RD_B(buf, nq, breg) do {                                                 \
        char* _p = lds + (buf) * 65536 + 32768 + wc * 8192 + (nq) * 4096 + rl;   \
        _Pragma("unroll")                                                        \
        for (int _n = 0; _n < 2; ++_n) {                                         \
            breg[_n][0] = *(const bf16x8*)(_p + _n * 2048 + kb0);                \
            breg[_n][1] = *(const bf16x8*)(_p + _n * 2048 + kb1);                \
        }                                                                        \
    } while (0)

#define MMA_Q(mq, nq, areg, breg) do {                                           \
        __builtin_amdgcn_s_setprio(1);                                           \
        _Pragma("unroll")                                                        \
        for (int _j = 0; _j < 4; ++_j)                                           \
        _Pragma("unroll")                                                        \
        for (int _n = 0; _n < 2; ++_n) {                                         \
            acc[(mq)*4+_j][(nq)*2+_n] = __builtin_amdgcn_mfma_f32_16x16x32_bf16( \
                areg[_j][0], breg[_n][0], acc[(mq)*4+_j][(nq)*2+_n], 0, 0, 0);   \
            acc[(mq)*4+_j][(nq)*2+_n] = __builtin_amdgcn_mfma_f32_16x16x32_bf16( \
                areg[_j][1], breg[_n][1], acc[(mq)*4+_j][(nq)*2+_n], 0, 0, 0);   \
        }                                                                        \
        __builtin_amdgcn_s_setprio(0);                                           \
    } while (0)

// one K-tile: reads (consumption order) -> stage next tile -> 4 MFMA quadrants
// -> vmcnt(0) + barrier (single sync point per tile).
#define TILE_BODY(buf, ktn) do {                                                 \
        RD_A(buf, 0, aA);                                                        \
        RD_B(buf, 0, b0);                                                        \
        RD_B(buf, 1, b1);                                                        \
        RD_A(buf, 1, aB);                                                        \
        STAGE(gA0, ((buf)^1) * 65536,         0, ktn);                           \
        STAGE(gA0, ((buf)^1) * 65536,         1, ktn);                           \
        STAGE(gB0, ((buf)^1) * 65536 + 32768, 0, ktn);                           \
        STAGE(gB0, ((buf)^1) * 65536 + 32768, 1, ktn);                           \
        MMA_Q(0, 0, aA, b0);                                                     \
        MMA_Q(0, 1, aA, b1);                                                     \
        MMA_Q(1, 1, aB, b1);                                                     \
        MMA_Q(1, 0, aB, b0);                                                     \
        VMC0(); BAR();                                                           \
    } while (0)

    // prologue: stage tile 0 into buf0
    STAGE(gA0, 0,     0, 0);
    STAGE(gA0, 0,     1, 0);
    STAGE(gB0, 32768, 0, 0);
    STAGE(gB0, 32768, 1, 0);
    VMC0();
    BAR();

    #pragma unroll 1
    for (int it = 0; it < KT / 2; ++it) {
        const int kt1 = 2 * it + 1;                               // < KT always
        const int kt2 = (2 * it + 2 < KT) ? 2 * it + 2 : KT - 1;  // clamp: benign restage
        TILE_BODY(0, kt1);
        TILE_BODY(1, kt2);
    }

    // epilogue: nt stores — C write-once, keep L2/L3 for A/B
    const int er = m0 + wr * 128 + (lane >> 4) * 4;
    const int ec = n0 + wc * 64 + (lane & 15);
    #pragma unroll
    for (int ni = 0; ni < 4; ++ni) {
        const float bv = bias[ec + ni * 16];
        #pragma unroll
        for (int mi = 0; mi < 8; ++mi) {
            #pragma unroll
            for (int r = 0; r < 4; ++r) {
                __builtin_nontemporal_store(
                    acc[mi][ni][r] + bv,
                    &C[(long)(er + mi * 16 + r) * OUT_F + ec + ni * 16]);
            }
        }
    }
}

extern "C" void kernel_launch(void* const* d_in, const int* in_sizes, int n_in,
                              void* d_out, int out_size, void* d_ws, size_t ws_size,
                              hipStream_t stream) {
    const float* x    = (const float*)d_in[0];
    const int*   hw   = (const int*)d_in[1];
    const float* hs   = (const float*)d_in[2];
    const int*   lw   = (const int*)d_in[3];
    const float* s1   = (const float*)d_in[4];
    const float* s2   = (const float*)d_in[5];
    const float* zp   = (const float*)d_in[6];
    const int*   cinv = (const int*)d_in[7];
    const float* bias = (const float*)d_in[8];
    float*       out  = (float*)d_out;

    short* wt  = (short*)d_ws;                                     // 90,177,536 B
    short* xb  = (short*)((char*)d_ws + (size_t)OUT_F * IN_F * 2); // +33,554,432 B
    int*   fwd = (int*)((char*)d_ws + (size_t)OUT_F * IN_F * 2
                                    + (size_t)M_TOT * IN_F * 2);   // +44,032 B

    fwd_perm_kernel<<<(OUT_F + 255) / 256, 256, 0, stream>>>(cinv, fwd);
    cvt_x_kernel<<<2048, 256, 0, stream>>>(x, xb);
    dequant_kernel<<<dim3(OUT_F / 64, IN_F / 64), 256, 0, stream>>>(
        hw, hs, lw, s1, s2, zp, fwd, wt);
    gemm_kernel<<<NWG2, 512, 0, stream>>>(xb, wt, bias, out);
}